// Round 15
// baseline (230.917 us; speedup 1.0000x reference)
//
#include <hip/hip_runtime.h>

#define DIM 512
#define H 256
#define W 256

// ---------------------------------------------------------------------------
// Fused prep kernel (unchanged from round 10 — measured good).
// Blocks 0..48: fold 3 depthwise kernels into one 7x7 tap table (transposed
// grid => tap w[c, dw+pad, dh+pad]) + bias sum. Blocks 49..: scatter point
// indices onto cell->index map. NO memset: gather validates entries.
// ---------------------------------------------------------------------------
__global__ __launch_bounds__(512) void prep_kernel(
    const int* __restrict__ pos, int n,
    const float* __restrict__ k3, const float* __restrict__ b1,
    const float* __restrict__ k5, const float* __restrict__ b2,
    const float* __restrict__ k7, const float* __restrict__ b3,
    float* __restrict__ weff, float* __restrict__ bsum,
    int* __restrict__ map) {
    int b = blockIdx.x;
    if (b < 49) {
        int o = b;             // 0..48
        int c = threadIdx.x;   // 0..511
        int dh = o / 7 - 3, dw = o % 7 - 3;
        float v = k7[c * 49 + (dw + 3) * 7 + (dh + 3)];
        if (dh >= -2 && dh <= 2 && dw >= -2 && dw <= 2)
            v += k5[c * 25 + (dw + 2) * 5 + (dh + 2)];
        if (dh >= -1 && dh <= 1 && dw >= -1 && dw <= 1)
            v += k3[c * 9 + (dw + 1) * 3 + (dh + 1)];
        weff[o * DIM + c] = v;
        if (o == 0) bsum[c] = b1[c] + b2[c] + b3[c];
    } else {
        int i = (b - 49) * 512 + threadIdx.x;
        if (i < n) {
            int h = pos[2 * i], w = pos[2 * i + 1];
            map[h * W + w] = i;
        }
    }
}

// ---------------------------------------------------------------------------
// Gather-conv v3: ONE WAVE PER POINT. Block = 128 threads = 2 waves = 2
// consecutive points (after XCD-chunked group swizzle). Each lane owns 8
// channels (2x float4), so each neighbor iteration issues 4 independent
// 16B loads (w0,w1,x0,x1) — explicit 2-stage software pipeline keeps the
// next neighbor's loads in flight during the current neighbor's FMAs.
// Probes run in parallel per wave (own s_list). Map entries are validated
// against pos (no memset needed; poison rejected by bounds+coords check).
// out[i,c] = x[i,c] + bsum[c] + sum_valid Weff[o,c] * x[j,c]
// ---------------------------------------------------------------------------
__global__ __launch_bounds__(128) void gather_conv_kernel(
    const float* __restrict__ x, const int2* __restrict__ pos2,
    const int* __restrict__ map, const float* __restrict__ weff,
    const float* __restrict__ bsum, float* __restrict__ out, int n) {
    int g = blockIdx.x;
    int ng = gridDim.x;
    // bijective XCD-chunked swizzle when ng % 8 == 0 (ng = 16384)
    int gs = ((ng & 7) == 0) ? ((g & 7) * (ng >> 3) + (g >> 3)) : g;
    int wv = threadIdx.x >> 6;      // wave id: 0 or 1
    int lane = threadIdx.x & 63;
    int i = gs * 2 + wv;
    bool valid = (i < n);

    __shared__ int s_list[2][49];
    __shared__ int s_cnt[2];
    if (lane == 0) s_cnt[wv] = 0;
    __syncthreads();

    if (valid && lane < 49) {
        int2 pw = pos2[i];
        int dh = lane / 7 - 3, dw = lane % 7 - 3;
        int hh = pw.x + dh, ww = pw.y + dw;
        if (hh >= 0 && hh < H && ww >= 0 && ww < W) {
            int j = map[hh * W + ww];
            if ((unsigned)j < (unsigned)n) {
                int2 pj = pos2[j];
                if (pj.x == hh && pj.y == ww) {
                    int slot = atomicAdd(&s_cnt[wv], 1);
                    s_list[wv][slot] = (j << 6) | lane;  // pack: j | offset
                }
            }
        }
    }
    __syncthreads();

    if (!valid) return;

    int c = lane * 8;
    const float* xi = x + (size_t)i * DIM + c;
    float4 acc0 = *(const float4*)(xi);
    float4 acc1 = *(const float4*)(xi + 4);
    float4 b0 = *(const float4*)(bsum + c);
    float4 b1 = *(const float4*)(bsum + c + 4);
    acc0.x += b0.x; acc0.y += b0.y; acc0.z += b0.z; acc0.w += b0.w;
    acc1.x += b1.x; acc1.y += b1.y; acc1.z += b1.z; acc1.w += b1.w;

    int cnt = s_cnt[wv];
    const int* lst = s_list[wv];

    if (cnt > 0) {
        // stage 0: issue first neighbor's loads
        int pk = lst[0];
        const float* wp = weff + (pk & 63) * DIM + c;
        const float* xp = x + (size_t)(pk >> 6) * DIM + c;
        float4 wa0 = *(const float4*)(wp);
        float4 wa1 = *(const float4*)(wp + 4);
        float4 xa0 = *(const float4*)(xp);
        float4 xa1 = *(const float4*)(xp + 4);
        for (int k = 1; k < cnt; ++k) {
            // issue next neighbor's loads BEFORE consuming current
            int pk2 = lst[k];
            const float* wp2 = weff + (pk2 & 63) * DIM + c;
            const float* xp2 = x + (size_t)(pk2 >> 6) * DIM + c;
            float4 wb0 = *(const float4*)(wp2);
            float4 wb1 = *(const float4*)(wp2 + 4);
            float4 xb0 = *(const float4*)(xp2);
            float4 xb1 = *(const float4*)(xp2 + 4);
            acc0.x = fmaf(wa0.x, xa0.x, acc0.x);
            acc0.y = fmaf(wa0.y, xa0.y, acc0.y);
            acc0.z = fmaf(wa0.z, xa0.z, acc0.z);
            acc0.w = fmaf(wa0.w, xa0.w, acc0.w);
            acc1.x = fmaf(wa1.x, xa1.x, acc1.x);
            acc1.y = fmaf(wa1.y, xa1.y, acc1.y);
            acc1.z = fmaf(wa1.z, xa1.z, acc1.z);
            acc1.w = fmaf(wa1.w, xa1.w, acc1.w);
            wa0 = wb0; wa1 = wb1; xa0 = xb0; xa1 = xb1;
        }
        acc0.x = fmaf(wa0.x, xa0.x, acc0.x);
        acc0.y = fmaf(wa0.y, xa0.y, acc0.y);
        acc0.z = fmaf(wa0.z, xa0.z, acc0.z);
        acc0.w = fmaf(wa0.w, xa0.w, acc0.w);
        acc1.x = fmaf(wa1.x, xa1.x, acc1.x);
        acc1.y = fmaf(wa1.y, xa1.y, acc1.y);
        acc1.z = fmaf(wa1.z, xa1.z, acc1.z);
        acc1.w = fmaf(wa1.w, xa1.w, acc1.w);
    }

    float* op = out + (size_t)i * DIM + c;
    *(float4*)(op) = acc0;
    *(float4*)(op + 4) = acc1;
}

extern "C" void kernel_launch(void* const* d_in, const int* in_sizes, int n_in,
                              void* d_out, int out_size, void* d_ws, size_t ws_size,
                              hipStream_t stream) {
    const float* x   = (const float*)d_in[0];
    const int*   pos = (const int*)d_in[1];
    const float* k3  = (const float*)d_in[2];
    const float* b1  = (const float*)d_in[3];
    const float* k5  = (const float*)d_in[4];
    const float* b2  = (const float*)d_in[5];
    const float* k7  = (const float*)d_in[6];
    const float* b3  = (const float*)d_in[7];
    float* out = (float*)d_out;

    char* ws = (char*)d_ws;
    int*   map  = (int*)ws;                                   // H*W*4   = 256 KB
    float* weff = (float*)(ws + (size_t)H * W * 4);           // 49*512*4 ~ 100 KB
    float* bsum = (float*)(ws + (size_t)H * W * 4 + 49 * DIM * 4);  // 2 KB

    int n = in_sizes[1] / 2;  // N points

    int scatter_blocks = (n + 511) / 512;
    prep_kernel<<<49 + scatter_blocks, 512, 0, stream>>>(
        pos, n, k3, b1, k5, b2, k7, b3, weff, bsum, map);
    int ngroups = (n + 1) / 2;
    gather_conv_kernel<<<ngroups, 128, 0, stream>>>(
        x, (const int2*)pos, map, weff, bsum, out, n);
}